// Round 7
// baseline (433.367 us; speedup 1.0000x reference)
//
#include <hip/hip_runtime.h>
#include <cstdint>

#define N_NODES 50000
#define N_EDGES 1600000
#define NH 4
#define CC 32
#define HC 128          // NH*CC
#define LAT 32
#define NEG_SLOPE 0.2f

// fused k_pre role split: [hist | node | v | w1t | w2t]
#define NB_HIST 250                      // 250 x 6400-edge chunks
#define CH_E    6400
#define NB_NODE 25                       // node: 2048 nodes per block
#define NB_PRE  (NB_HIST + NB_NODE + 3)  // +v +w1t +w2t

// bucketed scatter: bucket = dst >> 8 (256 nodes / bucket)
#define NBUCK 196                        // ceil(50000/256)
#define P1_T  512
#define P1_EPB (P1_T * 4)                // 2048 edges per phase-1 block
#define P1_BLOCKS ((N_EDGES + P1_EPB - 1) / P1_EPB)   // 782

typedef uint32_t u32x4 __attribute__((ext_vector_type(4)));
typedef __bf16   bf16x8 __attribute__((ext_vector_type(8)));
typedef float    f32x4 __attribute__((ext_vector_type(4)));

// ---------------- bf16 helpers (RNE pack, shift-unpack) ----------------
__device__ __forceinline__ float bflo(uint32_t u) {
    union { uint32_t i; float f; } c; c.i = u << 16; return c.f;
}
__device__ __forceinline__ float bfhi(uint32_t u) {
    union { uint32_t i; float f; } c; c.i = u & 0xFFFF0000u; return c.f;
}
__device__ __forceinline__ uint32_t f2bf(float f) {
    union { float f; uint32_t i; } c; c.f = f;
    return (c.i + 0x7FFFu + ((c.i >> 16) & 1u)) >> 16;
}
__device__ __forceinline__ uint32_t pack2(float a, float b) {
    return f2bf(a) | (f2bf(b) << 16);
}
// fp8 e4m3fn pack/unpack (ae only feeds the self-loop mean -> 6% rel err ok)
__device__ __forceinline__ uint32_t f2e4m3(float x) {
    uint32_t u = __float_as_uint(x);
    uint32_t s = u >> 31;
    uint32_t mag = u & 0x7fffffffu;
    mag += 0x7ffffu + ((mag >> 20) & 1u);       // RNE at bit 20
    uint32_t e = mag >> 23;
    if (e < 121u) return s << 7;                // underflow -> 0
    uint32_t code = ((e - 120u) << 3) | ((mag >> 20) & 7u);
    if (code > 0x7Eu) code = 0x7Eu;             // clamp to 448
    return (s << 7) | code;
}
__device__ __forceinline__ float e4m32f(uint32_t b) {
    uint32_t e = (b >> 3) & 15u;
    if (e == 0u) return 0.f;
    return __uint_as_float(((b >> 7) << 31) | ((e + 120u) << 23) | ((b & 7u) << 20));
}

// ---------------------------------------------------------------- kernels

// fused front end: [hist | node | v | w1t | w2t] by blockIdx range
__global__ __launch_bounds__(256) void k_pre(const float* __restrict__ x,
                                             const int* __restrict__ ei,
                                             const float* __restrict__ W_gat,
                                             const float* __restrict__ att_src,
                                             const float* __restrict__ att_dst,
                                             const float* __restrict__ W_edge,
                                             const float* __restrict__ att_edge,
                                             const float* __restrict__ W1,
                                             const float* __restrict__ W2,
                                             uint16_t* __restrict__ hist,
                                             float4* __restrict__ a_src,
                                             float4* __restrict__ a_dst,
                                             float* __restrict__ v,
                                             uint16_t* __restrict__ W1T_hi,
                                             uint16_t* __restrict__ W1T_lo,
                                             uint16_t* __restrict__ W2T_hi,
                                             uint16_t* __restrict__ W2T_lo) {
    __shared__ uint32_t lh[12500];             // hist: 25000 uint16 bins/pass
    int bid = blockIdx.x, t = threadIdx.x;
    if (bid < NB_HIST) {
        // atomic-free degree histogram (uint16 pairs packed in uint32)
        int b = bid;
        int base = b * CH_E;
        uint32_t* orow = (uint32_t*)(hist + (size_t)b * N_NODES);
        #pragma unroll 1
        for (int p = 0; p < 2; ++p) {
            for (int i = t; i < 12500; i += 256) lh[i] = 0;
            __syncthreads();
            int lo = p * 25000;
            #pragma unroll 1
            for (int it = 0; it < CH_E / 256; ++it) {
                int dst = ei[N_EDGES + base + it * 256 + t];
                int r = dst - lo;
                if (r >= 0 && r < 25000)
                    atomicAdd(&lh[r >> 1], 1u << ((r & 1) * 16));
            }
            __syncthreads();
            for (int i = t; i < 12500; i += 256)
                orow[p * 12500 + i] = lh[i];
            __syncthreads();
        }
    } else if (bid < NB_HIST + NB_NODE) {
        __shared__ float us[12], ud[12];
        if (t < 12) {
            int i = t >> 2, h = t & 3;
            float s = 0.f;
            #pragma unroll
            for (int c = 0; c < 32; ++c)
                s += W_gat[i * 128 + h * 32 + c] * att_src[h * 32 + c];
            us[t] = s;
        } else if (t < 24) {
            int q = t - 12; int i = q >> 2, h = q & 3;
            float s = 0.f;
            #pragma unroll
            for (int c = 0; c < 32; ++c)
                s += W_gat[i * 128 + h * 32 + c] * att_dst[h * 32 + c];
            ud[q] = s;
        }
        __syncthreads();
        int base = (bid - NB_HIST) * 2048;
        #pragma unroll 1
        for (int i = 0; i < 8; ++i) {
            int n = base + i * 256 + t;
            if (n >= N_NODES) break;
            float x0 = x[n * 3 + 0], x1 = x[n * 3 + 1], x2 = x[n * 3 + 2];
            float s[4], d[4];
            #pragma unroll
            for (int h = 0; h < 4; ++h) {
                s[h] = x0 * us[h] + x1 * us[4 + h] + x2 * us[8 + h];
                d[h] = x0 * ud[h] + x1 * ud[4 + h] + x2 * ud[8 + h];
            }
            a_src[n] = make_float4(s[0], s[1], s[2], s[3]);
            a_dst[n] = make_float4(d[0], d[1], d[2], d[3]);
        }
    } else if (bid == NB_HIST + NB_NODE) {
        if (t < 28) {
            int d = t >> 2, h = t & 3;
            float s = 0.f;
            #pragma unroll
            for (int c = 0; c < 32; ++c)
                s += W_edge[d * 128 + h * 32 + c] * att_edge[h * 32 + c];
            v[t] = s;
        }
    } else if (bid == NB_HIST + NB_NODE + 1) {
        // W1T bf16 hi/lo planes: W1T[n][k] = W1[k][n]
        #pragma unroll 4
        for (int i = 0; i < 64; ++i) {
            int idx = i * 256 + t;             // 16384
            int n = idx >> 7, k = idx & 127;
            float vv = W1[k * 128 + n];
            uint32_t hi = f2bf(vv);
            uint32_t lo = f2bf(vv - bflo(hi));
            W1T_hi[idx] = (uint16_t)hi;
            W1T_lo[idx] = (uint16_t)lo;
        }
    } else {
        // W2T bf16 hi/lo planes: W2T[j][k] = W2[k][j]
        #pragma unroll 4
        for (int i = 0; i < 16; ++i) {
            int idx = i * 256 + t;             // 4096
            int j = idx >> 7, k = idx & 127;
            float vv = W2[k * 32 + j];
            uint32_t hi = f2bf(vv);
            uint32_t lo = f2bf(vv - bflo(hi));
            W2T_hi[idx] = (uint16_t)hi;
            W2T_lo[idx] = (uint16_t)lo;
        }
    }
}

// sum the 250 partial histograms per node -> cnt; block = bucket -> bsum[b]
__global__ __launch_bounds__(256) void k_red(const uint16_t* __restrict__ hist,
                                             int* __restrict__ cnt,
                                             int* __restrict__ bsum) {
    __shared__ int red[256];
    int t = threadIdx.x;
    int i = blockIdx.x * 256 + t;
    int run = 0;
    if (i < N_NODES) {
        int r[10];
        #pragma unroll
        for (int j = 0; j < 10; ++j) r[j] = 0;
        size_t off = i;
        #pragma unroll 1
        for (int b = 0; b < 25; ++b) {
            #pragma unroll
            for (int j = 0; j < 10; ++j)
                r[j] += hist[off + (size_t)j * N_NODES];
            off += (size_t)10 * N_NODES;
        }
        #pragma unroll
        for (int j = 1; j < 10; ++j) r[0] += r[j];
        run = r[0];
        cnt[i] = run;
    }
    red[t] = run;
    __syncthreads();
    #pragma unroll
    for (int s = 128; s > 0; s >>= 1) {
        if (t < s) red[t] += red[t + s];
        __syncthreads();
    }
    if (t == 0) bsum[blockIdx.x] = red[0];
}

// single tiny block: exclusive scan of 196 bucket sums -> bbase[0..196] + bcur
__global__ __launch_bounds__(256) void k_scanb(const int* __restrict__ bsum,
                                               int* __restrict__ bbase,
                                               int* __restrict__ bcur) {
    __shared__ int sh[256];
    int t = threadIdx.x;
    int vv = (t < NBUCK) ? bsum[t] : 0;
    sh[t] = vv;
    __syncthreads();
    #pragma unroll
    for (int off = 1; off < 256; off <<= 1) {
        int xv = (t >= off) ? sh[t - off] : 0;
        __syncthreads();
        sh[t] += xv;
        __syncthreads();
    }
    if (t < NBUCK) { bbase[t] = sh[t] - vv; bcur[t] = sh[t] - vv; }
    if (t == 255) bbase[NBUCK] = sh[255];      // grand total (= N_EDGES)
}

// scatter: compute records (comb = ae + a_src, 4xfp8 ae in pad word,
// dst&255 in bits 16..23 of the src word), stage bucket-partitioned.
// v2: records are placed into a bucket-sorted LDS staging array (block-local
// scan of the bucket histogram -> LDS offsets; gaddr[slot] = global target);
// copy-out walks slots linearly so consecutive lanes store to mostly
// consecutive addresses (runs of ~10) -> ~10x fewer store transactions.
__global__ __launch_bounds__(512) void k_scat1(const int* __restrict__ ei,
                                               const float* __restrict__ edge_attr,
                                               const float* __restrict__ v,
                                               const float4* __restrict__ a_src,
                                               int* __restrict__ bcur,
                                               uint4* __restrict__ stg) {
    __shared__ int bh[NBUCK];        // per-block bucket histogram
    __shared__ int bg[NBUCK];        // this block's global base per bucket
    __shared__ int bl[NBUCK];        // local cursor per bucket
    __shared__ int bo[NBUCK];        // block-local exclusive offset per bucket
    __shared__ int sct[256];         // scan temp
    __shared__ u32x4 lrec[P1_EPB];   // bucket-sorted records (32KB)
    __shared__ int gaddr[P1_EPB];    // global slot per record (8KB)
    int t = threadIdx.x;
    float vsr[28];
    #pragma unroll
    for (int i = 0; i < 28; ++i) vsr[i] = v[i];   // uniform addr -> s_load

    for (int i = t; i < NBUCK; i += P1_T) bh[i] = 0;
    __syncthreads();

    int e0 = blockIdx.x * P1_EPB + t * 4;          // 4 consecutive edges
    bool act = (e0 < N_EDGES);                     // tail is a multiple of 4
    int dst[4];
    uint4 rec[4];
    if (act) {
        int4 s4 = *(const int4*)&ei[e0];
        int4 d4 = *(const int4*)&ei[N_EDGES + e0];
        int srcv[4] = {s4.x, s4.y, s4.z, s4.w};
        dst[0] = d4.x; dst[1] = d4.y; dst[2] = d4.z; dst[3] = d4.w;

        float4 as4[4];
        #pragma unroll
        for (int q = 0; q < 4; ++q)
            as4[q] = a_src[srcv[q]];               // L2-resident 800KB table

        const float4* ea4 = (const float4*)&edge_attr[e0 * 7];
        float ea[28];
        #pragma unroll
        for (int i = 0; i < 7; ++i) {
            float4 vv = ea4[i];
            ea[i * 4 + 0] = vv.x; ea[i * 4 + 1] = vv.y;
            ea[i * 4 + 2] = vv.z; ea[i * 4 + 3] = vv.w;
        }

        #pragma unroll
        for (int q = 0; q < 4; ++q) {
            float asv[4] = {as4[q].x, as4[q].y, as4[q].z, as4[q].w};
            float comb[4];
            uint32_t ae8 = 0;
            #pragma unroll
            for (int h = 0; h < 4; ++h) {
                float aeh = 0.f;
                #pragma unroll
                for (int d = 0; d < 7; ++d) aeh += ea[q * 7 + d] * vsr[d * 4 + h];
                ae8 |= f2e4m3(aeh) << (h * 8);
                comb[h] = aeh + asv[h];
            }
            rec[q] = make_uint4(pack2(comb[0], comb[1]), pack2(comb[2], comb[3]),
                                (uint32_t)srcv[q] | ((uint32_t)(dst[q] & 255) << 16),
                                ae8);
            atomicAdd(&bh[dst[q] >> 8], 1);
        }
    }
    __syncthreads();
    // block-local exclusive scan of bh (196 -> 256-wide Hillis-Steele)
    int hv = 0;
    if (t < 256) { hv = (t < NBUCK) ? bh[t] : 0; sct[t] = hv; }
    __syncthreads();
    #pragma unroll
    for (int off = 1; off < 256; off <<= 1) {
        int xv = 0;
        if (t < 256 && t >= off) xv = sct[t - off];
        __syncthreads();
        if (t < 256) sct[t] += xv;
        __syncthreads();
    }
    if (t < NBUCK) {
        bo[t] = sct[t] - hv;                       // local exclusive base
        bg[t] = hv ? atomicAdd(&bcur[t], hv) : 0;  // global run base
        bl[t] = 0;
    }
    __syncthreads();
    if (act) {
        #pragma unroll
        for (int q = 0; q < 4; ++q) {
            int bk = dst[q] >> 8;
            int off = atomicAdd(&bl[bk], 1);       // fast LDS cursor
            int slot = bo[bk] + off;
            lrec[slot] = (u32x4){rec[q].x, rec[q].y, rec[q].z, rec[q].w};
            gaddr[slot] = bg[bk] + off;
        }
    }
    __syncthreads();
    int total = sct[255];                          // records in this block
    for (int s = t; s < total; s += P1_T) {
        u32x4 r = lrec[s];
        stg[gaddr[s]] = make_uint4(r.x, r.y, r.z, r.w);
    }
}

// fused gather: one block per bucket (256 nodes). Streams the bucket's stg
// slice ONCE; per-(node,head) state is 5 floats {sum w*x0..x2, sum w, sum ae}
// accumulated via LDS float atomics (valid because w = exp(al) needs no max
// pass). Then finalize: self-loop, W_gat projection, ELU -> h_buf.
// Replaces k_scat2 + csr + old k_gather (saves 76.8MB of csr traffic).
__global__ __launch_bounds__(1024) void k_gat2(const int* __restrict__ bbase,
                                               const int* __restrict__ cnt,
                                               const uint4* __restrict__ stg,
                                               const float* __restrict__ x,
                                               const float* __restrict__ a_src,
                                               const float* __restrict__ a_dst,
                                               const float* __restrict__ W_gat,
                                               const float* __restrict__ bias_gat,
                                               float2* __restrict__ h_buf) {
    __shared__ float acc[256 * 20];   // [node][head][5]: sx0,sx1,sx2,den,aes
    int b = blockIdx.x, t = threadIdx.x;
    int n0 = b << 8;
    int nn = min(256, N_NODES - n0);
    #pragma unroll
    for (int i = t; i < 256 * 20; i += 1024) acc[i] = 0.f;
    __syncthreads();

    int lo = bbase[b], hi = bbase[b + 1];
    for (int e = lo + t; e < hi; e += 1024) {
        uint4 rec = stg[e];
        int src = (int)(rec.z & 0xFFFFu);
        int dl  = (int)((rec.z >> 16) & 0xFFu);
        float4 ad = ((const float4*)a_dst)[n0 + dl];   // 4KB window, L1-hot
        const float* xr = x + src * 3;                 // 600KB table, L2-hot
        float x0 = xr[0], x1 = xr[1], x2 = xr[2];
        float* ap = acc + dl * 20;
        float adh[4] = {ad.x, ad.y, ad.z, ad.w};
        #pragma unroll
        for (int h = 0; h < 4; ++h) {
            uint32_t aw = (h < 2) ? rec.x : rec.y;
            float comb = (h & 1) ? bfhi(aw) : bflo(aw);   // ae + a_src[src]
            float ae = e4m32f((rec.w >> (h * 8)) & 0xffu);
            float al = comb + adh[h];
            al = al > 0.f ? al : NEG_SLOPE * al;
            float w = __expf(al);
            atomicAdd(ap + h * 5 + 0, w * x0);
            atomicAdd(ap + h * 5 + 1, w * x1);
            atomicAdd(ap + h * 5 + 2, w * x2);
            atomicAdd(ap + h * 5 + 3, w);
            atomicAdd(ap + h * 5 + 4, ae);
        }
    }
    __syncthreads();

    // finalize: 16 node-groups x 64 lanes; lane l -> head l>>4, channels 2l,2l+1
    int g = t >> 6, l = t & 63;
    int h = l >> 4;
    int c0 = 2 * l;
    float w00 = W_gat[c0],       w01 = W_gat[c0 + 1];
    float w10 = W_gat[128 + c0], w11 = W_gat[128 + c0 + 1];
    float w20 = W_gat[256 + c0], w21 = W_gat[256 + c0 + 1];
    float2 bia = ((const float2*)bias_gat)[l];
    for (int i = g; i < nn; i += 16) {
        int n = n0 + i;
        const float* ap = acc + i * 20 + h * 5;        // broadcast reads
        float t0 = ap[0], t1 = ap[1], t2 = ap[2], td = ap[3], aes = ap[4];
        int deg = cnt[n];
        float ad_n = a_dst[n * 4 + h];
        float as_n = a_src[n * 4 + h];
        float invd = (deg > 0) ? (1.0f / (float)deg) : 1.0f;
        float alS = as_n + ad_n + aes * invd;          // self-loop (mean ae)
        alS = alS > 0.f ? alS : NEG_SLOPE * alS;
        float wS = __expf(alS);
        float xn0 = x[n * 3], xn1 = x[n * 3 + 1], xn2 = x[n * 3 + 2];
        t0 += wS * xn0; t1 += wS * xn1; t2 += wS * xn2; td += wS;
        float r = 1.0f / td;
        float o0 = (t0 * w00 + t1 * w10 + t2 * w20) * r + bia.x;
        float o1 = (t0 * w01 + t1 * w11 + t2 * w21) * r + bia.y;
        o0 = o0 > 0.f ? o0 : (__expf(o0) - 1.0f);      // ELU
        o1 = o1 > 0.f ? o1 : (__expf(o1) - 1.0f);
        h_buf[(size_t)n * 64 + l] = make_float2(o0, o1);
    }
}

// MFMA MLP: 32 rows/block, 4 waves. bf16 hi/lo split (3-term) for ~fp32
// accuracy at matrix-pipe rate. LDS planes [32][136] bf16 (row stride 272B).
__global__ __launch_bounds__(256) void k_mlp(const float* __restrict__ h_buf,
                                             const uint16_t* __restrict__ W1T_hi,
                                             const uint16_t* __restrict__ W1T_lo,
                                             const uint16_t* __restrict__ W2T_hi,
                                             const uint16_t* __restrict__ W2T_lo,
                                             const float* __restrict__ b1,
                                             const float* __restrict__ prelu_a,
                                             const float* __restrict__ b2,
                                             float* __restrict__ out) {
    __shared__ uint16_t hHi[32 * 136];
    __shared__ uint16_t hLo[32 * 136];
    __shared__ uint16_t h1Hi[32 * 136];
    __shared__ uint16_t h1Lo[32 * 136];
    int t = threadIdx.x;
    int nb = blockIdx.x * 32;

    // stage h rows -> bf16 hi/lo planes
    const float4* hb4 = (const float4*)(h_buf + (size_t)nb * 128);
    #pragma unroll
    for (int i = 0; i < 4; ++i) {
        int idx = i * 256 + t;             // float4 index, 1024 total
        int row = idx >> 5, c4 = idx & 31;
        float4 v = make_float4(0.f, 0.f, 0.f, 0.f);
        if (nb + row < N_NODES) v = hb4[idx];
        float xs[4] = {v.x, v.y, v.z, v.w};
        uint32_t hi[4], lo[4];
        #pragma unroll
        for (int j = 0; j < 4; ++j) {
            hi[j] = f2bf(xs[j]);
            lo[j] = f2bf(xs[j] - bflo(hi[j]));
        }
        uint32_t bo = row * 272 + c4 * 8;
        *(uint2*)((char*)hHi + bo) = make_uint2(hi[0] | (hi[1] << 16), hi[2] | (hi[3] << 16));
        *(uint2*)((char*)hLo + bo) = make_uint2(lo[0] | (lo[1] << 16), lo[2] | (lo[3] << 16));
    }
    __syncthreads();

    int w = t >> 6, l = t & 63;
    int lr = l & 15, lg = l >> 4;          // frag row/col lane, k-group
    // ---- layer 1: wave w -> col-tiles {2w, 2w+1}, both row-tiles ----
    float bb0 = b1[(2 * w) * 16 + lr];
    float bb1 = b1[(2 * w + 1) * 16 + lr];
    f32x4 acc[2][2];
    #pragma unroll
    for (int rt = 0; rt < 2; ++rt) {
        acc[rt][0] = (f32x4){bb0, bb0, bb0, bb0};
        acc[rt][1] = (f32x4){bb1, bb1, bb1, bb1};
    }
    #pragma unroll
    for (int s = 0; s < 4; ++s) {
        int koff = s * 64 + lg * 16;       // byte offset of k-chunk
        bf16x8 a_hi[2], a_lo[2], b_hi[2], b_lo[2];
        #pragma unroll
        for (int rt = 0; rt < 2; ++rt) {
            int ro = (rt * 16 + lr) * 272 + koff;
            a_hi[rt] = *(const bf16x8*)((const char*)hHi + ro);
            a_lo[rt] = *(const bf16x8*)((const char*)hLo + ro);
        }
        #pragma unroll
        for (int c = 0; c < 2; ++c) {
            int go = ((2 * w + c) * 16 + lr) * 256 + koff;
            b_hi[c] = *(const bf16x8*)((const char*)W1T_hi + go);
            b_lo[c] = *(const bf16x8*)((const char*)W1T_lo + go);
        }
        #pragma unroll
        for (int rt = 0; rt < 2; ++rt)
            #pragma unroll
            for (int c = 0; c < 2; ++c) {
                acc[rt][c] = __builtin_amdgcn_mfma_f32_16x16x32_bf16(a_hi[rt], b_hi[c], acc[rt][c], 0, 0, 0);
                acc[rt][c] = __builtin_amdgcn_mfma_f32_16x16x32_bf16(a_hi[rt], b_lo[c], acc[rt][c], 0, 0, 0);
                acc[rt][c] = __builtin_amdgcn_mfma_f32_16x16x32_bf16(a_lo[rt], b_hi[c], acc[rt][c], 0, 0, 0);
            }
    }
    // PReLU + re-split -> h1 planes
    float pa = prelu_a[0];
    #pragma unroll
    for (int rt = 0; rt < 2; ++rt)
        #pragma unroll
        for (int c = 0; c < 2; ++c) {
            int n = (2 * w + c) * 16 + lr;
            #pragma unroll
            for (int r = 0; r < 4; ++r) {
                float vv = acc[rt][c][r];
                vv = vv > 0.f ? vv : pa * vv;
                uint32_t hi = f2bf(vv);
                uint32_t lo = f2bf(vv - bflo(hi));
                int m = rt * 16 + lg * 4 + r;
                uint32_t bo = m * 272 + n * 2;
                *(uint16_t*)((char*)h1Hi + bo) = (uint16_t)hi;
                *(uint16_t*)((char*)h1Lo + bo) = (uint16_t)lo;
            }
        }
    __syncthreads();
    // ---- layer 2: wave w -> tile (rt = w&1, ct = w>>1) ----
    int rt2 = w & 1, ct2 = w >> 1;
    float bb2 = b2[ct2 * 16 + lr];
    f32x4 acc2 = (f32x4){bb2, bb2, bb2, bb2};
    #pragma unroll
    for (int s = 0; s < 4; ++s) {
        int koff = s * 64 + lg * 16;
        int ro = (rt2 * 16 + lr) * 272 + koff;
        bf16x8 a_hi = *(const bf16x8*)((const char*)h1Hi + ro);
        bf16x8 a_lo = *(const bf16x8*)((const char*)h1Lo + ro);
        int go = (ct2 * 16 + lr) * 256 + koff;
        bf16x8 w2h = *(const bf16x8*)((const char*)W2T_hi + go);
        bf16x8 w2l = *(const bf16x8*)((const char*)W2T_lo + go);
        acc2 = __builtin_amdgcn_mfma_f32_16x16x32_bf16(a_hi, w2h, acc2, 0, 0, 0);
        acc2 = __builtin_amdgcn_mfma_f32_16x16x32_bf16(a_hi, w2l, acc2, 0, 0, 0);
        acc2 = __builtin_amdgcn_mfma_f32_16x16x32_bf16(a_lo, w2h, acc2, 0, 0, 0);
    }
    #pragma unroll
    for (int r = 0; r < 4; ++r) {
        int m = rt2 * 16 + lg * 4 + r;
        if (nb + m < N_NODES)
            out[(size_t)(nb + m) * 32 + ct2 * 16 + lr] = acc2[r];
    }
}

// ---------------------------------------------------------------- launch

extern "C" void kernel_launch(void* const* d_in, const int* in_sizes, int n_in,
                              void* d_out, int out_size, void* d_ws, size_t ws_size,
                              hipStream_t stream) {
    const float* x        = (const float*)d_in[0];
    const int*   ei       = (const int*)d_in[1];     // int32 per harness contract
    const float* edge_attr= (const float*)d_in[2];
    const float* W_gat    = (const float*)d_in[3];
    const float* att_src  = (const float*)d_in[4];
    const float* att_dst  = (const float*)d_in[5];
    const float* W_edge   = (const float*)d_in[6];
    const float* att_edge = (const float*)d_in[7];
    const float* bias_gat = (const float*)d_in[8];
    const float* W1       = (const float*)d_in[9];
    const float* b1       = (const float*)d_in[10];
    const float* prelu_a  = (const float*)d_in[11];
    const float* W2       = (const float*)d_in[12];
    const float* b2       = (const float*)d_in[13];
    float*       out      = (float*)d_out;

    char* base = (char*)d_ws;
    size_t off = 0;
    auto alloc = [&](size_t bytes) -> void* {
        void* p = base + off;
        off = (off + bytes + 255) & ~(size_t)255;
        return p;
    };
    int*      cnt     = (int*)     alloc((size_t)N_NODES * 4);
    int*      bcur    = (int*)     alloc((size_t)NBUCK * 4);
    int*      bsum    = (int*)     alloc((size_t)NBUCK * 4);
    int*      bbase   = (int*)     alloc((size_t)(NBUCK + 1) * 4);
    float*    v       = (float*)   alloc(32 * 4);
    uint16_t* W1T_hi  = (uint16_t*)alloc((size_t)128 * 128 * 2);
    uint16_t* W1T_lo  = (uint16_t*)alloc((size_t)128 * 128 * 2);
    uint16_t* W2T_hi  = (uint16_t*)alloc((size_t)32 * 128 * 2);
    uint16_t* W2T_lo  = (uint16_t*)alloc((size_t)32 * 128 * 2);
    float*    a_src   = (float*)   alloc((size_t)N_NODES * 4 * 4);
    float*    a_dst   = (float*)   alloc((size_t)N_NODES * 4 * 4);
    float*    h_buf   = (float*)   alloc((size_t)N_NODES * 128 * 4);
    // staging aliases the hist buffer: hist is dead after k_red, staging is
    // written only after k_scanb. region = max(25.0MB hist, 25.6MB staging).
    size_t stg_bytes  = (size_t)N_EDGES * 16;
    size_t hist_bytes = (size_t)NB_HIST * N_NODES * 2;
    void* stg_region  = alloc(stg_bytes > hist_bytes ? stg_bytes : hist_bytes);
    uint16_t* hist    = (uint16_t*)stg_region;
    uint4*    stg     = (uint4*)stg_region;

    k_pre  <<<NB_PRE, 256, 0, stream>>>(x, ei, W_gat, att_src, att_dst,
                                        W_edge, att_edge, W1, W2, hist,
                                        (float4*)a_src, (float4*)a_dst, v,
                                        W1T_hi, W1T_lo, W2T_hi, W2T_lo);
    k_red  <<<NBUCK, 256, 0, stream>>>(hist, cnt, bsum);
    k_scanb<<<1, 256, 0, stream>>>(bsum, bbase, bcur);
    k_scat1<<<P1_BLOCKS, P1_T, 0, stream>>>(
        ei, edge_attr, v, (const float4*)a_src, bcur, stg);
    k_gat2 <<<NBUCK, 1024, 0, stream>>>(
        bbase, cnt, stg, x, a_src, a_dst, W_gat, bias_gat, (float2*)h_buf);
    k_mlp  <<<(N_NODES + 31) / 32, 256, 0, stream>>>(
        h_buf, W1T_hi, W1T_lo, W2T_hi, W2T_lo, b1, prelu_a, b2, out);
}

// Round 8
// 252.380 us; speedup vs baseline: 1.7171x; 1.7171x over previous
//
#include <hip/hip_runtime.h>
#include <cstdint>

#define N_NODES 50000
#define N_EDGES 1600000
#define NH 4
#define CC 32
#define HC 128          // NH*CC
#define LAT 32
#define NEG_SLOPE 0.2f

// fused k_pre role split: [hist | node | v | w1t | w2t]
#define NB_HIST 250                      // 250 x 6400-edge chunks
#define CH_E    6400
#define NB_NODE 25                       // node: 2048 nodes per block
#define NB_PRE  (NB_HIST + NB_NODE + 3)  // +v +w1t +w2t

// two-phase bucketed scatter: bucket = dst >> 8 (256 nodes / bucket)
#define NBUCK 196                        // ceil(50000/256)
#define P1_T  512
#define P1_EPB (P1_T * 4)                // 2048 edges per phase-1 block
#define P1_BLOCKS ((N_EDGES + P1_EPB - 1) / P1_EPB)   // 782

typedef uint32_t u32x4 __attribute__((ext_vector_type(4)));
typedef __bf16   bf16x8 __attribute__((ext_vector_type(8)));
typedef float    f32x4 __attribute__((ext_vector_type(4)));

// ---------------- bf16 helpers (RNE pack, shift-unpack) ----------------
__device__ __forceinline__ float bflo(uint32_t u) {
    union { uint32_t i; float f; } c; c.i = u << 16; return c.f;
}
__device__ __forceinline__ float bfhi(uint32_t u) {
    union { uint32_t i; float f; } c; c.i = u & 0xFFFF0000u; return c.f;
}
__device__ __forceinline__ uint32_t f2bf(float f) {
    union { float f; uint32_t i; } c; c.f = f;
    return (c.i + 0x7FFFu + ((c.i >> 16) & 1u)) >> 16;
}
__device__ __forceinline__ uint32_t pack2(float a, float b) {
    return f2bf(a) | (f2bf(b) << 16);
}
__device__ __forceinline__ float bpermf(int byteIdx, float v) {
    return __int_as_float(__builtin_amdgcn_ds_bpermute(byteIdx, __float_as_int(v)));
}
// fp8 e4m3fn pack/unpack (ae only feeds the self-loop mean -> 6% rel err ok)
__device__ __forceinline__ uint32_t f2e4m3(float x) {
    uint32_t u = __float_as_uint(x);
    uint32_t s = u >> 31;
    uint32_t mag = u & 0x7fffffffu;
    mag += 0x7ffffu + ((mag >> 20) & 1u);       // RNE at bit 20
    uint32_t e = mag >> 23;
    if (e < 121u) return s << 7;                // underflow -> 0
    uint32_t code = ((e - 120u) << 3) | ((mag >> 20) & 7u);
    if (code > 0x7Eu) code = 0x7Eu;             // clamp to 448
    return (s << 7) | code;
}
__device__ __forceinline__ float e4m32f(uint32_t b) {
    uint32_t e = (b >> 3) & 15u;
    if (e == 0u) return 0.f;
    return __uint_as_float(((b >> 7) << 31) | ((e + 120u) << 23) | ((b & 7u) << 20));
}

// ---------------------------------------------------------------- kernels

// fused front end: [hist | node | v | w1t | w2t] by blockIdx range
__global__ __launch_bounds__(256) void k_pre(const float* __restrict__ x,
                                             const int* __restrict__ ei,
                                             const float* __restrict__ W_gat,
                                             const float* __restrict__ att_src,
                                             const float* __restrict__ att_dst,
                                             const float* __restrict__ W_edge,
                                             const float* __restrict__ att_edge,
                                             const float* __restrict__ W1,
                                             const float* __restrict__ W2,
                                             uint16_t* __restrict__ hist,
                                             float4* __restrict__ a_src,
                                             float4* __restrict__ a_dst,
                                             float* __restrict__ v,
                                             uint16_t* __restrict__ W1T_hi,
                                             uint16_t* __restrict__ W1T_lo,
                                             uint16_t* __restrict__ W2T_hi,
                                             uint16_t* __restrict__ W2T_lo) {
    __shared__ uint32_t lh[12500];             // hist: 25000 uint16 bins/pass
    int bid = blockIdx.x, t = threadIdx.x;
    if (bid < NB_HIST) {
        // atomic-free degree histogram (uint16 pairs packed in uint32)
        int b = bid;
        int base = b * CH_E;
        uint32_t* orow = (uint32_t*)(hist + (size_t)b * N_NODES);
        #pragma unroll 1
        for (int p = 0; p < 2; ++p) {
            for (int i = t; i < 12500; i += 256) lh[i] = 0;
            __syncthreads();
            int lo = p * 25000;
            #pragma unroll 1
            for (int it = 0; it < CH_E / 256; ++it) {
                int dst = ei[N_EDGES + base + it * 256 + t];
                int r = dst - lo;
                if (r >= 0 && r < 25000)
                    atomicAdd(&lh[r >> 1], 1u << ((r & 1) * 16));
            }
            __syncthreads();
            for (int i = t; i < 12500; i += 256)
                orow[p * 12500 + i] = lh[i];
            __syncthreads();
        }
    } else if (bid < NB_HIST + NB_NODE) {
        __shared__ float us[12], ud[12];
        if (t < 12) {
            int i = t >> 2, h = t & 3;
            float s = 0.f;
            #pragma unroll
            for (int c = 0; c < 32; ++c)
                s += W_gat[i * 128 + h * 32 + c] * att_src[h * 32 + c];
            us[t] = s;
        } else if (t < 24) {
            int q = t - 12; int i = q >> 2, h = q & 3;
            float s = 0.f;
            #pragma unroll
            for (int c = 0; c < 32; ++c)
                s += W_gat[i * 128 + h * 32 + c] * att_dst[h * 32 + c];
            ud[q] = s;
        }
        __syncthreads();
        int base = (bid - NB_HIST) * 2048;
        #pragma unroll 1
        for (int i = 0; i < 8; ++i) {
            int n = base + i * 256 + t;
            if (n >= N_NODES) break;
            float x0 = x[n * 3 + 0], x1 = x[n * 3 + 1], x2 = x[n * 3 + 2];
            float s[4], d[4];
            #pragma unroll
            for (int h = 0; h < 4; ++h) {
                s[h] = x0 * us[h] + x1 * us[4 + h] + x2 * us[8 + h];
                d[h] = x0 * ud[h] + x1 * ud[4 + h] + x2 * ud[8 + h];
            }
            a_src[n] = make_float4(s[0], s[1], s[2], s[3]);
            a_dst[n] = make_float4(d[0], d[1], d[2], d[3]);
        }
    } else if (bid == NB_HIST + NB_NODE) {
        if (t < 28) {
            int d = t >> 2, h = t & 3;
            float s = 0.f;
            #pragma unroll
            for (int c = 0; c < 32; ++c)
                s += W_edge[d * 128 + h * 32 + c] * att_edge[h * 32 + c];
            v[t] = s;
        }
    } else if (bid == NB_HIST + NB_NODE + 1) {
        // W1T bf16 hi/lo planes: W1T[n][k] = W1[k][n]
        #pragma unroll 4
        for (int i = 0; i < 64; ++i) {
            int idx = i * 256 + t;             // 16384
            int n = idx >> 7, k = idx & 127;
            float vv = W1[k * 128 + n];
            uint32_t hi = f2bf(vv);
            uint32_t lo = f2bf(vv - bflo(hi));
            W1T_hi[idx] = (uint16_t)hi;
            W1T_lo[idx] = (uint16_t)lo;
        }
    } else {
        // W2T bf16 hi/lo planes: W2T[j][k] = W2[k][j]
        #pragma unroll 4
        for (int i = 0; i < 16; ++i) {
            int idx = i * 256 + t;             // 4096
            int j = idx >> 7, k = idx & 127;
            float vv = W2[k * 32 + j];
            uint32_t hi = f2bf(vv);
            uint32_t lo = f2bf(vv - bflo(hi));
            W2T_hi[idx] = (uint16_t)hi;
            W2T_lo[idx] = (uint16_t)lo;
        }
    }
}

// sum the 250 partial histograms per node -> cnt; block = bucket -> bsum[b]
__global__ __launch_bounds__(256) void k_red(const uint16_t* __restrict__ hist,
                                             int* __restrict__ cnt,
                                             int* __restrict__ bsum) {
    __shared__ int red[256];
    int t = threadIdx.x;
    int i = blockIdx.x * 256 + t;
    int run = 0;
    if (i < N_NODES) {
        int r[10];
        #pragma unroll
        for (int j = 0; j < 10; ++j) r[j] = 0;
        size_t off = i;
        #pragma unroll 1
        for (int b = 0; b < 25; ++b) {
            #pragma unroll
            for (int j = 0; j < 10; ++j)
                r[j] += hist[off + (size_t)j * N_NODES];
            off += (size_t)10 * N_NODES;
        }
        #pragma unroll
        for (int j = 1; j < 10; ++j) r[0] += r[j];
        run = r[0];
        cnt[i] = run;
    }
    red[t] = run;
    __syncthreads();
    #pragma unroll
    for (int s = 128; s > 0; s >>= 1) {
        if (t < s) red[t] += red[t + s];
        __syncthreads();
    }
    if (t == 0) bsum[blockIdx.x] = red[0];
}

// single tiny block: exclusive scan of 196 bucket sums -> bbase[0..196]
__global__ __launch_bounds__(256) void k_scanb(const int* __restrict__ bsum,
                                               int* __restrict__ bbase) {
    __shared__ int sh[256];
    int t = threadIdx.x;
    int vv = (t < NBUCK) ? bsum[t] : 0;
    sh[t] = vv;
    __syncthreads();
    #pragma unroll
    for (int off = 1; off < 256; off <<= 1) {
        int xv = (t >= off) ? sh[t - off] : 0;
        __syncthreads();
        sh[t] += xv;
        __syncthreads();
    }
    if (t < NBUCK) bbase[t] = sh[t] - vv;      // exclusive
    if (t == 255) bbase[NBUCK] = sh[255];      // grand total (= N_EDGES)
}

// per-bucket local scan: rowptr slice + bcur (phase-1 bucket cursors)
__global__ __launch_bounds__(256) void k_local(const int* __restrict__ cnt,
                                               const int* __restrict__ bbase,
                                               int* __restrict__ rowptr,
                                               int* __restrict__ bcur) {
    __shared__ int sh[256];
    int b = blockIdx.x, t = threadIdx.x;
    int i = b * 256 + t;
    int vv = (i < N_NODES) ? cnt[i] : 0;
    sh[t] = vv;
    __syncthreads();
    #pragma unroll
    for (int off = 1; off < 256; off <<= 1) {
        int xv = (t >= off) ? sh[t - off] : 0;
        __syncthreads();
        sh[t] += xv;
        __syncthreads();
    }
    int base = bbase[b];
    if (i < N_NODES) rowptr[i] = base + sh[t] - vv;
    if (t == 0) bcur[b] = base;
    if (b == 0 && t == 0) rowptr[N_NODES] = bbase[NBUCK];
}

// scatter: compute records (comb = ae + a_src, 4xfp8 ae in pad word,
// dst&255 in bits 16..23 of the src word), stage bucket-partitioned.
// v2: records are placed into a bucket-sorted LDS staging array (block-local
// scan of the bucket histogram -> LDS offsets; gaddr[slot] = global target);
// copy-out walks slots linearly so consecutive lanes store to mostly
// consecutive addresses (runs of ~10) -> ~10x fewer store transactions.
__global__ __launch_bounds__(512) void k_scat1(const int* __restrict__ ei,
                                               const float* __restrict__ edge_attr,
                                               const float* __restrict__ v,
                                               const float4* __restrict__ a_src,
                                               int* __restrict__ bcur,
                                               uint4* __restrict__ stg) {
    __shared__ int bh[NBUCK];        // per-block bucket histogram
    __shared__ int bg[NBUCK];        // this block's global base per bucket
    __shared__ int bl[NBUCK];        // local cursor per bucket
    __shared__ int bo[NBUCK];        // block-local exclusive offset per bucket
    __shared__ int sct[256];         // scan temp
    __shared__ u32x4 lrec[P1_EPB];   // bucket-sorted records (32KB)
    __shared__ int gaddr[P1_EPB];    // global slot per record (8KB)
    int t = threadIdx.x;
    float vsr[28];
    #pragma unroll
    for (int i = 0; i < 28; ++i) vsr[i] = v[i];   // uniform addr -> s_load

    for (int i = t; i < NBUCK; i += P1_T) bh[i] = 0;
    __syncthreads();

    int e0 = blockIdx.x * P1_EPB + t * 4;          // 4 consecutive edges
    bool act = (e0 < N_EDGES);                     // tail is a multiple of 4
    int dst[4];
    uint4 rec[4];
    if (act) {
        int4 s4 = *(const int4*)&ei[e0];
        int4 d4 = *(const int4*)&ei[N_EDGES + e0];
        int srcv[4] = {s4.x, s4.y, s4.z, s4.w};
        dst[0] = d4.x; dst[1] = d4.y; dst[2] = d4.z; dst[3] = d4.w;

        float4 as4[4];
        #pragma unroll
        for (int q = 0; q < 4; ++q)
            as4[q] = a_src[srcv[q]];               // L2-resident 800KB table

        const float4* ea4 = (const float4*)&edge_attr[e0 * 7];
        float ea[28];
        #pragma unroll
        for (int i = 0; i < 7; ++i) {
            float4 vv = ea4[i];
            ea[i * 4 + 0] = vv.x; ea[i * 4 + 1] = vv.y;
            ea[i * 4 + 2] = vv.z; ea[i * 4 + 3] = vv.w;
        }

        #pragma unroll
        for (int q = 0; q < 4; ++q) {
            float asv[4] = {as4[q].x, as4[q].y, as4[q].z, as4[q].w};
            float comb[4];
            uint32_t ae8 = 0;
            #pragma unroll
            for (int h = 0; h < 4; ++h) {
                float aeh = 0.f;
                #pragma unroll
                for (int d = 0; d < 7; ++d) aeh += ea[q * 7 + d] * vsr[d * 4 + h];
                ae8 |= f2e4m3(aeh) << (h * 8);
                comb[h] = aeh + asv[h];
            }
            rec[q] = make_uint4(pack2(comb[0], comb[1]), pack2(comb[2], comb[3]),
                                (uint32_t)srcv[q] | ((uint32_t)(dst[q] & 255) << 16),
                                ae8);
            atomicAdd(&bh[dst[q] >> 8], 1);
        }
    }
    __syncthreads();
    // block-local exclusive scan of bh (196 -> 256-wide Hillis-Steele)
    int hv = 0;
    if (t < 256) { hv = (t < NBUCK) ? bh[t] : 0; sct[t] = hv; }
    __syncthreads();
    #pragma unroll
    for (int off = 1; off < 256; off <<= 1) {
        int xv = 0;
        if (t < 256 && t >= off) xv = sct[t - off];
        __syncthreads();
        if (t < 256) sct[t] += xv;
        __syncthreads();
    }
    if (t < NBUCK) {
        bo[t] = sct[t] - hv;                       // local exclusive base
        bg[t] = hv ? atomicAdd(&bcur[t], hv) : 0;  // global run base
        bl[t] = 0;
    }
    __syncthreads();
    if (act) {
        #pragma unroll
        for (int q = 0; q < 4; ++q) {
            int bk = dst[q] >> 8;
            int off = atomicAdd(&bl[bk], 1);       // fast LDS cursor
            int slot = bo[bk] + off;
            lrec[slot] = (u32x4){rec[q].x, rec[q].y, rec[q].z, rec[q].w};
            gaddr[slot] = bg[bk] + off;
        }
    }
    __syncthreads();
    int total = sct[255];                          // records in this block
    for (int s = t; s < total; s += P1_T) {
        u32x4 r = lrec[s];
        stg[gaddr[s]] = make_uint4(r.x, r.y, r.z, r.w);
    }
}

// scatter phase 2: one block per bucket. Sequential (non-temporal) read of the
// staged slice; per-node placement counters in LDS; writes confined to a
// ~130KB csr window resident in one XCD's L2 -> full-line writebacks.
__global__ __launch_bounds__(1024) void k_scat2(const int* __restrict__ rowptr,
                                                const uint4* __restrict__ stg,
                                                uint4* __restrict__ csr) {
    __shared__ int rp[257];
    __shared__ int lcnt[256];
    int b = blockIdx.x, t = threadIdx.x;
    int n0 = b << 8;
    int nn = min(256, N_NODES - n0);
    for (int i = t; i <= nn; i += 1024) rp[i] = rowptr[n0 + i];
    __syncthreads();
    for (int i = t; i < nn; i += 1024) lcnt[i] = rp[i + 1] - rp[i];
    __syncthreads();
    int lo = rp[0], hi = rp[nn];

    int e = lo + t;
    u32x4 r = {};
    if (e < hi) r = __builtin_nontemporal_load((const u32x4*)(stg + e));
    while (e < hi) {
        int en = e + 1024;
        u32x4 rn = {};
        if (en < hi) rn = __builtin_nontemporal_load((const u32x4*)(stg + en));
        int dl = (int)((r.z >> 16) & 0xFFu);
        int c = atomicSub(&lcnt[dl], 1);
        csr[rp[dl] + c - 1] = make_uint4(r.x, r.y, r.z, r.w);
        r = rn; e = en;
    }
}

// gather v3: aggregate raw x (3-dim, 600KB L2-resident) instead of xp.
// Linearity: sum(w*xp[src]) = (sum(w*x[src])) @ W_gat, self-loop included
// before projection. Lane = (slot 0..15, head = l&3); 16 edges/pass, 4 lanes
// share one record; xor-reduce {4,8,16,32} over slots; bpermute head totals;
// each lane projects its 2 channels (6 W_gat scalars).
__global__ __launch_bounds__(128) void k_gather(const int* __restrict__ rowptr,
                                                const uint4* __restrict__ csr,
                                                const float* __restrict__ x,
                                                const float* __restrict__ a_src,
                                                const float* __restrict__ a_dst,
                                                const float* __restrict__ W_gat,
                                                const float* __restrict__ bias_gat,
                                                float2* __restrict__ h_buf) {
    int n = blockIdx.x * 2 + (threadIdx.x >> 6);
    int l = threadIdx.x & 63;
    int h = l & 3;                 // aggregation head
    int slot = l >> 2;             // edge slot 0..15
    int start = rowptr[n], end = rowptr[n + 1];
    int deg = end - start;

    float ad_n = a_dst[n * 4 + h];
    float as_n = a_src[n * 4 + h];

    float sx0 = 0.f, sx1 = 0.f, sx2 = 0.f, den = 0.f, aes = 0.f;

    for (int p0 = start; p0 < end; p0 += 16) {
        int e = p0 + slot;
        float w = 0.f, ae = 0.f;
        int src = n;
        if (e < end) {
            uint4 rec = csr[e];
            uint32_t aw = (h < 2) ? rec.x : rec.y;
            float comb = (h & 1) ? bfhi(aw) : bflo(aw);   // ae + a_src[src]
            ae = e4m32f((rec.w >> (h * 8)) & 0xffu);
            src = (int)(rec.z & 0xFFFFu);
            float al = comb + ad_n;
            al = al > 0.f ? al : NEG_SLOPE * al;
            w = __expf(al);
        }
        const float* xr = x + src * 3;                    // L2-hot 600KB table
        sx0 += w * xr[0];
        sx1 += w * xr[1];
        sx2 += w * xr[2];
        den += w;
        aes += ae;
    }

    // reduce across the 16 slots (lanes with equal l&3)
    #pragma unroll
    for (int m = 4; m <= 32; m <<= 1) {
        sx0 += __shfl_xor(sx0, m);
        sx1 += __shfl_xor(sx1, m);
        sx2 += __shfl_xor(sx2, m);
        den += __shfl_xor(den, m);
        aes += __shfl_xor(aes, m);
    }

    // self loop: edge_attr = mean of incoming aeh (linearity of the .v dot)
    float xn0 = x[n * 3], xn1 = x[n * 3 + 1], xn2 = x[n * 3 + 2];
    float invd = (deg > 0) ? (1.0f / (float)deg) : 1.0f;
    float alS = as_n + ad_n + aes * invd;
    alS = alS > 0.f ? alS : NEG_SLOPE * alS;
    float wS = __expf(alS);
    sx0 += wS * xn0; sx1 += wS * xn1; sx2 += wS * xn2;
    den += wS;

    // redistribute: lane l needs head p = l>>4 totals; lane p holds head p
    int sb = (l >> 4) << 2;        // bpermute byteIdx = src lane * 4
    float t0 = bpermf(sb, sx0);
    float t1 = bpermf(sb, sx1);
    float t2 = bpermf(sb, sx2);
    float td = bpermf(sb, den);

    // project: channels c0=2l, 2l+1 (head = l>>4 matches c>>5)
    int c0 = 2 * l;
    float w00 = W_gat[c0],       w01 = W_gat[c0 + 1];
    float w10 = W_gat[128 + c0], w11 = W_gat[128 + c0 + 1];
    float w20 = W_gat[256 + c0], w21 = W_gat[256 + c0 + 1];
    float r = 1.0f / td;
    float2 bia = ((const float2*)bias_gat)[l];
    float o0 = (t0 * w00 + t1 * w10 + t2 * w20) * r + bia.x;
    float o1 = (t0 * w01 + t1 * w11 + t2 * w21) * r + bia.y;
    o0 = o0 > 0.f ? o0 : (__expf(o0) - 1.0f);   // ELU
    o1 = o1 > 0.f ? o1 : (__expf(o1) - 1.0f);
    h_buf[n * 64 + l] = make_float2(o0, o1);
}

// MFMA MLP: 32 rows/block, 4 waves. bf16 hi/lo split (3-term) for ~fp32
// accuracy at matrix-pipe rate. LDS planes [32][136] bf16 (row stride 272B).
__global__ __launch_bounds__(256) void k_mlp(const float* __restrict__ h_buf,
                                             const uint16_t* __restrict__ W1T_hi,
                                             const uint16_t* __restrict__ W1T_lo,
                                             const uint16_t* __restrict__ W2T_hi,
                                             const uint16_t* __restrict__ W2T_lo,
                                             const float* __restrict__ b1,
                                             const float* __restrict__ prelu_a,
                                             const float* __restrict__ b2,
                                             float* __restrict__ out) {
    __shared__ uint16_t hHi[32 * 136];
    __shared__ uint16_t hLo[32 * 136];
    __shared__ uint16_t h1Hi[32 * 136];
    __shared__ uint16_t h1Lo[32 * 136];
    int t = threadIdx.x;
    int nb = blockIdx.x * 32;

    // stage h rows -> bf16 hi/lo planes
    const float4* hb4 = (const float4*)(h_buf + (size_t)nb * 128);
    #pragma unroll
    for (int i = 0; i < 4; ++i) {
        int idx = i * 256 + t;             // float4 index, 1024 total
        int row = idx >> 5, c4 = idx & 31;
        float4 v = make_float4(0.f, 0.f, 0.f, 0.f);
        if (nb + row < N_NODES) v = hb4[idx];
        float xs[4] = {v.x, v.y, v.z, v.w};
        uint32_t hi[4], lo[4];
        #pragma unroll
        for (int j = 0; j < 4; ++j) {
            hi[j] = f2bf(xs[j]);
            lo[j] = f2bf(xs[j] - bflo(hi[j]));
        }
        uint32_t bo = row * 272 + c4 * 8;
        *(uint2*)((char*)hHi + bo) = make_uint2(hi[0] | (hi[1] << 16), hi[2] | (hi[3] << 16));
        *(uint2*)((char*)hLo + bo) = make_uint2(lo[0] | (lo[1] << 16), lo[2] | (lo[3] << 16));
    }
    __syncthreads();

    int w = t >> 6, l = t & 63;
    int lr = l & 15, lg = l >> 4;          // frag row/col lane, k-group
    // ---- layer 1: wave w -> col-tiles {2w, 2w+1}, both row-tiles ----
    float bb0 = b1[(2 * w) * 16 + lr];
    float bb1 = b1[(2 * w + 1) * 16 + lr];
    f32x4 acc[2][2];
    #pragma unroll
    for (int rt = 0; rt < 2; ++rt) {
        acc[rt][0] = (f32x4){bb0, bb0, bb0, bb0};
        acc[rt][1] = (f32x4){bb1, bb1, bb1, bb1};
    }
    #pragma unroll
    for (int s = 0; s < 4; ++s) {
        int koff = s * 64 + lg * 16;       // byte offset of k-chunk
        bf16x8 a_hi[2], a_lo[2], b_hi[2], b_lo[2];
        #pragma unroll
        for (int rt = 0; rt < 2; ++rt) {
            int ro = (rt * 16 + lr) * 272 + koff;
            a_hi[rt] = *(const bf16x8*)((const char*)hHi + ro);
            a_lo[rt] = *(const bf16x8*)((const char*)hLo + ro);
        }
        #pragma unroll
        for (int c = 0; c < 2; ++c) {
            int go = ((2 * w + c) * 16 + lr) * 256 + koff;
            b_hi[c] = *(const bf16x8*)((const char*)W1T_hi + go);
            b_lo[c] = *(const bf16x8*)((const char*)W1T_lo + go);
        }
        #pragma unroll
        for (int rt = 0; rt < 2; ++rt)
            #pragma unroll
            for (int c = 0; c < 2; ++c) {
                acc[rt][c] = __builtin_amdgcn_mfma_f32_16x16x32_bf16(a_hi[rt], b_hi[c], acc[rt][c], 0, 0, 0);
                acc[rt][c] = __builtin_amdgcn_mfma_f32_16x16x32_bf16(a_hi[rt], b_lo[c], acc[rt][c], 0, 0, 0);
                acc[rt][c] = __builtin_amdgcn_mfma_f32_16x16x32_bf16(a_lo[rt], b_hi[c], acc[rt][c], 0, 0, 0);
            }
    }
    // PReLU + re-split -> h1 planes
    float pa = prelu_a[0];
    #pragma unroll
    for (int rt = 0; rt < 2; ++rt)
        #pragma unroll
        for (int c = 0; c < 2; ++c) {
            int n = (2 * w + c) * 16 + lr;
            #pragma unroll
            for (int r = 0; r < 4; ++r) {
                float vv = acc[rt][c][r];
                vv = vv > 0.f ? vv : pa * vv;
                uint32_t hi = f2bf(vv);
                uint32_t lo = f2bf(vv - bflo(hi));
                int m = rt * 16 + lg * 4 + r;
                uint32_t bo = m * 272 + n * 2;
                *(uint16_t*)((char*)h1Hi + bo) = (uint16_t)hi;
                *(uint16_t*)((char*)h1Lo + bo) = (uint16_t)lo;
            }
        }
    __syncthreads();
    // ---- layer 2: wave w -> tile (rt = w&1, ct = w>>1) ----
    int rt2 = w & 1, ct2 = w >> 1;
    float bb2 = b2[ct2 * 16 + lr];
    f32x4 acc2 = (f32x4){bb2, bb2, bb2, bb2};
    #pragma unroll
    for (int s = 0; s < 4; ++s) {
        int koff = s * 64 + lg * 16;
        int ro = (rt2 * 16 + lr) * 272 + koff;
        bf16x8 a_hi = *(const bf16x8*)((const char*)h1Hi + ro);
        bf16x8 a_lo = *(const bf16x8*)((const char*)h1Lo + ro);
        int go = (ct2 * 16 + lr) * 256 + koff;
        bf16x8 w2h = *(const bf16x8*)((const char*)W2T_hi + go);
        bf16x8 w2l = *(const bf16x8*)((const char*)W2T_lo + go);
        acc2 = __builtin_amdgcn_mfma_f32_16x16x32_bf16(a_hi, w2h, acc2, 0, 0, 0);
        acc2 = __builtin_amdgcn_mfma_f32_16x16x32_bf16(a_hi, w2l, acc2, 0, 0, 0);
        acc2 = __builtin_amdgcn_mfma_f32_16x16x32_bf16(a_lo, w2h, acc2, 0, 0, 0);
    }
    #pragma unroll
    for (int r = 0; r < 4; ++r) {
        int m = rt2 * 16 + lg * 4 + r;
        if (nb + m < N_NODES)
            out[(size_t)(nb + m) * 32 + ct2 * 16 + lr] = acc2[r];
    }
}

// ---------------------------------------------------------------- launch

extern "C" void kernel_launch(void* const* d_in, const int* in_sizes, int n_in,
                              void* d_out, int out_size, void* d_ws, size_t ws_size,
                              hipStream_t stream) {
    const float* x        = (const float*)d_in[0];
    const int*   ei       = (const int*)d_in[1];     // int32 per harness contract
    const float* edge_attr= (const float*)d_in[2];
    const float* W_gat    = (const float*)d_in[3];
    const float* att_src  = (const float*)d_in[4];
    const float* att_dst  = (const float*)d_in[5];
    const float* W_edge   = (const float*)d_in[6];
    const float* att_edge = (const float*)d_in[7];
    const float* bias_gat = (const float*)d_in[8];
    const float* W1       = (const float*)d_in[9];
    const float* b1       = (const float*)d_in[10];
    const float* prelu_a  = (const float*)d_in[11];
    const float* W2       = (const float*)d_in[12];
    const float* b2       = (const float*)d_in[13];
    float*       out      = (float*)d_out;

    char* base = (char*)d_ws;
    size_t off = 0;
    auto alloc = [&](size_t bytes) -> void* {
        void* p = base + off;
        off = (off + bytes + 255) & ~(size_t)255;
        return p;
    };
    int*      cnt     = (int*)     alloc((size_t)N_NODES * 4);
    int*      rowptr  = (int*)     alloc((size_t)(N_NODES + 1) * 4);
    int*      bcur    = (int*)     alloc((size_t)NBUCK * 4);
    int*      bsum    = (int*)     alloc((size_t)NBUCK * 4);
    int*      bbase   = (int*)     alloc((size_t)(NBUCK + 1) * 4);
    float*    v       = (float*)   alloc(32 * 4);
    uint16_t* W1T_hi  = (uint16_t*)alloc((size_t)128 * 128 * 2);
    uint16_t* W1T_lo  = (uint16_t*)alloc((size_t)128 * 128 * 2);
    uint16_t* W2T_hi  = (uint16_t*)alloc((size_t)32 * 128 * 2);
    uint16_t* W2T_lo  = (uint16_t*)alloc((size_t)32 * 128 * 2);
    float*    a_src   = (float*)   alloc((size_t)N_NODES * 4 * 4);
    float*    a_dst   = (float*)   alloc((size_t)N_NODES * 4 * 4);
    uint4*    csr     = (uint4*)   alloc((size_t)N_EDGES * 16);
    float*    h_buf   = (float*)   alloc((size_t)N_NODES * 128 * 4);
    // staging aliases the hist buffer: hist is dead after k_red, staging is
    // written only after k_local. region = max(25.0MB hist, 25.6MB staging).
    size_t stg_bytes  = (size_t)N_EDGES * 16;
    size_t hist_bytes = (size_t)NB_HIST * N_NODES * 2;
    void* stg_region  = alloc(stg_bytes > hist_bytes ? stg_bytes : hist_bytes);
    uint16_t* hist    = (uint16_t*)stg_region;
    uint4*    stg     = (uint4*)stg_region;

    k_pre  <<<NB_PRE, 256, 0, stream>>>(x, ei, W_gat, att_src, att_dst,
                                        W_edge, att_edge, W1, W2, hist,
                                        (float4*)a_src, (float4*)a_dst, v,
                                        W1T_hi, W1T_lo, W2T_hi, W2T_lo);
    k_red  <<<NBUCK, 256, 0, stream>>>(hist, cnt, bsum);
    k_scanb<<<1, 256, 0, stream>>>(bsum, bbase);
    k_local<<<NBUCK, 256, 0, stream>>>(cnt, bbase, rowptr, bcur);
    k_scat1<<<P1_BLOCKS, P1_T, 0, stream>>>(
        ei, edge_attr, v, (const float4*)a_src, bcur, stg);
    k_scat2<<<NBUCK, 1024, 0, stream>>>(rowptr, stg, csr);
    k_gather<<<N_NODES / 2, 128, 0, stream>>>(
        rowptr, csr, x, a_src, a_dst, W_gat, bias_gat, (float2*)h_buf);
    k_mlp  <<<(N_NODES + 31) / 32, 256, 0, stream>>>(
        h_buf, W1T_hi, W1T_lo, W2T_hi, W2T_lo, b1, prelu_a, b2, out);
}

// Round 9
// 243.802 us; speedup vs baseline: 1.7775x; 1.0352x over previous
//
#include <hip/hip_runtime.h>
#include <cstdint>

#define N_NODES 50000
#define N_EDGES 1600000
#define NH 4
#define CC 32
#define HC 128          // NH*CC
#define LAT 32
#define NEG_SLOPE 0.2f

// fused k_pre role split: [hist | node | v | w1t | w2t]
#define NB_HIST 250                      // 250 x 6400-edge chunks
#define CH_E    6400
#define NB_NODE 25                       // node: 2048 nodes per block
#define NB_PRE  (NB_HIST + NB_NODE + 3)  // +v +w1t +w2t

// bucketed scatter: bucket = dst >> 8 (256 nodes / bucket)
#define NBUCK 196                        // ceil(50000/256)
#define P1_T  512
#define P1_EPB (P1_T * 4)                // 2048 edges per phase-1 block
#define P1_BLOCKS ((N_EDGES + P1_EPB - 1) / P1_EPB)   // 782
#define CAP  8960                        // LDS bucket capacity (mean 8192 + 8.5 sigma)

typedef uint32_t u32x4 __attribute__((ext_vector_type(4)));
typedef __bf16   bf16x8 __attribute__((ext_vector_type(8)));
typedef float    f32x4 __attribute__((ext_vector_type(4)));

// ---------------- bf16 helpers (RNE pack, shift-unpack) ----------------
__device__ __forceinline__ float bflo(uint32_t u) {
    union { uint32_t i; float f; } c; c.i = u << 16; return c.f;
}
__device__ __forceinline__ float bfhi(uint32_t u) {
    union { uint32_t i; float f; } c; c.i = u & 0xFFFF0000u; return c.f;
}
__device__ __forceinline__ uint32_t f2bf(float f) {
    union { float f; uint32_t i; } c; c.f = f;
    return (c.i + 0x7FFFu + ((c.i >> 16) & 1u)) >> 16;
}
__device__ __forceinline__ uint32_t pack2(float a, float b) {
    return f2bf(a) | (f2bf(b) << 16);
}
__device__ __forceinline__ float bpermf(int byteIdx, float v) {
    return __int_as_float(__builtin_amdgcn_ds_bpermute(byteIdx, __float_as_int(v)));
}
// fp8 e4m3fn pack/unpack (ae only feeds the self-loop mean -> 6% rel err ok)
__device__ __forceinline__ uint32_t f2e4m3(float x) {
    uint32_t u = __float_as_uint(x);
    uint32_t s = u >> 31;
    uint32_t mag = u & 0x7fffffffu;
    mag += 0x7ffffu + ((mag >> 20) & 1u);       // RNE at bit 20
    uint32_t e = mag >> 23;
    if (e < 121u) return s << 7;                // underflow -> 0
    uint32_t code = ((e - 120u) << 3) | ((mag >> 20) & 7u);
    if (code > 0x7Eu) code = 0x7Eu;             // clamp to 448
    return (s << 7) | code;
}
__device__ __forceinline__ float e4m32f(uint32_t b) {
    uint32_t e = (b >> 3) & 15u;
    if (e == 0u) return 0.f;
    return __uint_as_float(((b >> 7) << 31) | ((e + 120u) << 23) | ((b & 7u) << 20));
}

// ---------------------------------------------------------------- kernels

// fused front end: [hist | node | v | w1t | w2t] by blockIdx range
__global__ __launch_bounds__(256) void k_pre(const float* __restrict__ x,
                                             const int* __restrict__ ei,
                                             const float* __restrict__ W_gat,
                                             const float* __restrict__ att_src,
                                             const float* __restrict__ att_dst,
                                             const float* __restrict__ W_edge,
                                             const float* __restrict__ att_edge,
                                             const float* __restrict__ W1,
                                             const float* __restrict__ W2,
                                             uint16_t* __restrict__ hist,
                                             float4* __restrict__ a_src,
                                             float4* __restrict__ a_dst,
                                             float* __restrict__ v,
                                             uint16_t* __restrict__ W1T_hi,
                                             uint16_t* __restrict__ W1T_lo,
                                             uint16_t* __restrict__ W2T_hi,
                                             uint16_t* __restrict__ W2T_lo) {
    __shared__ uint32_t lh[12500];             // hist: 25000 uint16 bins/pass
    int bid = blockIdx.x, t = threadIdx.x;
    if (bid < NB_HIST) {
        // atomic-free degree histogram (uint16 pairs packed in uint32)
        int b = bid;
        int base = b * CH_E;
        uint32_t* orow = (uint32_t*)(hist + (size_t)b * N_NODES);
        #pragma unroll 1
        for (int p = 0; p < 2; ++p) {
            for (int i = t; i < 12500; i += 256) lh[i] = 0;
            __syncthreads();
            int lo = p * 25000;
            #pragma unroll 1
            for (int it = 0; it < CH_E / 256; ++it) {
                int dst = ei[N_EDGES + base + it * 256 + t];
                int r = dst - lo;
                if (r >= 0 && r < 25000)
                    atomicAdd(&lh[r >> 1], 1u << ((r & 1) * 16));
            }
            __syncthreads();
            for (int i = t; i < 12500; i += 256)
                orow[p * 12500 + i] = lh[i];
            __syncthreads();
        }
    } else if (bid < NB_HIST + NB_NODE) {
        __shared__ float us[12], ud[12];
        if (t < 12) {
            int i = t >> 2, h = t & 3;
            float s = 0.f;
            #pragma unroll
            for (int c = 0; c < 32; ++c)
                s += W_gat[i * 128 + h * 32 + c] * att_src[h * 32 + c];
            us[t] = s;
        } else if (t < 24) {
            int q = t - 12; int i = q >> 2, h = q & 3;
            float s = 0.f;
            #pragma unroll
            for (int c = 0; c < 32; ++c)
                s += W_gat[i * 128 + h * 32 + c] * att_dst[h * 32 + c];
            ud[q] = s;
        }
        __syncthreads();
        int base = (bid - NB_HIST) * 2048;
        #pragma unroll 1
        for (int i = 0; i < 8; ++i) {
            int n = base + i * 256 + t;
            if (n >= N_NODES) break;
            float x0 = x[n * 3 + 0], x1 = x[n * 3 + 1], x2 = x[n * 3 + 2];
            float s[4], d[4];
            #pragma unroll
            for (int h = 0; h < 4; ++h) {
                s[h] = x0 * us[h] + x1 * us[4 + h] + x2 * us[8 + h];
                d[h] = x0 * ud[h] + x1 * ud[4 + h] + x2 * ud[8 + h];
            }
            a_src[n] = make_float4(s[0], s[1], s[2], s[3]);
            a_dst[n] = make_float4(d[0], d[1], d[2], d[3]);
        }
    } else if (bid == NB_HIST + NB_NODE) {
        if (t < 28) {
            int d = t >> 2, h = t & 3;
            float s = 0.f;
            #pragma unroll
            for (int c = 0; c < 32; ++c)
                s += W_edge[d * 128 + h * 32 + c] * att_edge[h * 32 + c];
            v[t] = s;
        }
    } else if (bid == NB_HIST + NB_NODE + 1) {
        // W1T bf16 hi/lo planes: W1T[n][k] = W1[k][n]
        #pragma unroll 4
        for (int i = 0; i < 64; ++i) {
            int idx = i * 256 + t;             // 16384
            int n = idx >> 7, k = idx & 127;
            float vv = W1[k * 128 + n];
            uint32_t hi = f2bf(vv);
            uint32_t lo = f2bf(vv - bflo(hi));
            W1T_hi[idx] = (uint16_t)hi;
            W1T_lo[idx] = (uint16_t)lo;
        }
    } else {
        // W2T bf16 hi/lo planes: W2T[j][k] = W2[k][j]
        #pragma unroll 4
        for (int i = 0; i < 16; ++i) {
            int idx = i * 256 + t;             // 4096
            int j = idx >> 7, k = idx & 127;
            float vv = W2[k * 32 + j];
            uint32_t hi = f2bf(vv);
            uint32_t lo = f2bf(vv - bflo(hi));
            W2T_hi[idx] = (uint16_t)hi;
            W2T_lo[idx] = (uint16_t)lo;
        }
    }
}

// sum the 250 partial histograms per node -> cnt; block = bucket -> bsum[b]
__global__ __launch_bounds__(256) void k_red(const uint16_t* __restrict__ hist,
                                             int* __restrict__ cnt,
                                             int* __restrict__ bsum) {
    __shared__ int red[256];
    int t = threadIdx.x;
    int i = blockIdx.x * 256 + t;
    int run = 0;
    if (i < N_NODES) {
        int r[10];
        #pragma unroll
        for (int j = 0; j < 10; ++j) r[j] = 0;
        size_t off = i;
        #pragma unroll 1
        for (int b = 0; b < 25; ++b) {
            #pragma unroll
            for (int j = 0; j < 10; ++j)
                r[j] += hist[off + (size_t)j * N_NODES];
            off += (size_t)10 * N_NODES;
        }
        #pragma unroll
        for (int j = 1; j < 10; ++j) r[0] += r[j];
        run = r[0];
        cnt[i] = run;
    }
    red[t] = run;
    __syncthreads();
    #pragma unroll
    for (int s = 128; s > 0; s >>= 1) {
        if (t < s) red[t] += red[t + s];
        __syncthreads();
    }
    if (t == 0) bsum[blockIdx.x] = red[0];
}

// single tiny block: exclusive scan of 196 bucket sums -> bbase[0..196]
__global__ __launch_bounds__(256) void k_scanb(const int* __restrict__ bsum,
                                               int* __restrict__ bbase) {
    __shared__ int sh[256];
    int t = threadIdx.x;
    int vv = (t < NBUCK) ? bsum[t] : 0;
    sh[t] = vv;
    __syncthreads();
    #pragma unroll
    for (int off = 1; off < 256; off <<= 1) {
        int xv = (t >= off) ? sh[t - off] : 0;
        __syncthreads();
        sh[t] += xv;
        __syncthreads();
    }
    if (t < NBUCK) bbase[t] = sh[t] - vv;      // exclusive
    if (t == 255) bbase[NBUCK] = sh[255];      // grand total (= N_EDGES)
}

// per-bucket local scan: rowptr slice + bcur (phase-1 bucket cursors)
__global__ __launch_bounds__(256) void k_local(const int* __restrict__ cnt,
                                               const int* __restrict__ bbase,
                                               int* __restrict__ rowptr,
                                               int* __restrict__ bcur) {
    __shared__ int sh[256];
    int b = blockIdx.x, t = threadIdx.x;
    int i = b * 256 + t;
    int vv = (i < N_NODES) ? cnt[i] : 0;
    sh[t] = vv;
    __syncthreads();
    #pragma unroll
    for (int off = 1; off < 256; off <<= 1) {
        int xv = (t >= off) ? sh[t - off] : 0;
        __syncthreads();
        sh[t] += xv;
        __syncthreads();
    }
    int base = bbase[b];
    if (i < N_NODES) rowptr[i] = base + sh[t] - vv;
    if (t == 0) bcur[b] = base;
    if (b == 0 && t == 0) rowptr[N_NODES] = bbase[NBUCK];
}

// scatter: compute records (comb = ae + a_src, 4xfp8 ae in pad word,
// dst&255 in bits 16..23 of the src word), stage bucket-partitioned.
// LDS-bucket-sorted copy-out (runs of ~10 -> fewer store transactions).
__global__ __launch_bounds__(512) void k_scat1(const int* __restrict__ ei,
                                               const float* __restrict__ edge_attr,
                                               const float* __restrict__ v,
                                               const float4* __restrict__ a_src,
                                               int* __restrict__ bcur,
                                               uint4* __restrict__ stg) {
    __shared__ int bh[NBUCK];        // per-block bucket histogram
    __shared__ int bg[NBUCK];        // this block's global base per bucket
    __shared__ int bl[NBUCK];        // local cursor per bucket
    __shared__ int bo[NBUCK];        // block-local exclusive offset per bucket
    __shared__ int sct[256];         // scan temp
    __shared__ u32x4 lrec[P1_EPB];   // bucket-sorted records (32KB)
    __shared__ int gaddr[P1_EPB];    // global slot per record (8KB)
    int t = threadIdx.x;
    float vsr[28];
    #pragma unroll
    for (int i = 0; i < 28; ++i) vsr[i] = v[i];   // uniform addr -> s_load

    for (int i = t; i < NBUCK; i += P1_T) bh[i] = 0;
    __syncthreads();

    int e0 = blockIdx.x * P1_EPB + t * 4;          // 4 consecutive edges
    bool act = (e0 < N_EDGES);                     // tail is a multiple of 4
    int dst[4];
    uint4 rec[4];
    if (act) {
        int4 s4 = *(const int4*)&ei[e0];
        int4 d4 = *(const int4*)&ei[N_EDGES + e0];
        int srcv[4] = {s4.x, s4.y, s4.z, s4.w};
        dst[0] = d4.x; dst[1] = d4.y; dst[2] = d4.z; dst[3] = d4.w;

        float4 as4[4];
        #pragma unroll
        for (int q = 0; q < 4; ++q)
            as4[q] = a_src[srcv[q]];               // L2-resident 800KB table

        const float4* ea4 = (const float4*)&edge_attr[e0 * 7];
        float ea[28];
        #pragma unroll
        for (int i = 0; i < 7; ++i) {
            float4 vv = ea4[i];
            ea[i * 4 + 0] = vv.x; ea[i * 4 + 1] = vv.y;
            ea[i * 4 + 2] = vv.z; ea[i * 4 + 3] = vv.w;
        }

        #pragma unroll
        for (int q = 0; q < 4; ++q) {
            float asv[4] = {as4[q].x, as4[q].y, as4[q].z, as4[q].w};
            float comb[4];
            uint32_t ae8 = 0;
            #pragma unroll
            for (int h = 0; h < 4; ++h) {
                float aeh = 0.f;
                #pragma unroll
                for (int d = 0; d < 7; ++d) aeh += ea[q * 7 + d] * vsr[d * 4 + h];
                ae8 |= f2e4m3(aeh) << (h * 8);
                comb[h] = aeh + asv[h];
            }
            rec[q] = make_uint4(pack2(comb[0], comb[1]), pack2(comb[2], comb[3]),
                                (uint32_t)srcv[q] | ((uint32_t)(dst[q] & 255) << 16),
                                ae8);
            atomicAdd(&bh[dst[q] >> 8], 1);
        }
    }
    __syncthreads();
    // block-local exclusive scan of bh (196 -> 256-wide Hillis-Steele)
    int hv = 0;
    if (t < 256) { hv = (t < NBUCK) ? bh[t] : 0; sct[t] = hv; }
    __syncthreads();
    #pragma unroll
    for (int off = 1; off < 256; off <<= 1) {
        int xv = 0;
        if (t < 256 && t >= off) xv = sct[t - off];
        __syncthreads();
        if (t < 256) sct[t] += xv;
        __syncthreads();
    }
    if (t < NBUCK) {
        bo[t] = sct[t] - hv;                       // local exclusive base
        bg[t] = hv ? atomicAdd(&bcur[t], hv) : 0;  // global run base
        bl[t] = 0;
    }
    __syncthreads();
    if (act) {
        #pragma unroll
        for (int q = 0; q < 4; ++q) {
            int bk = dst[q] >> 8;
            int off = atomicAdd(&bl[bk], 1);       // fast LDS cursor
            int slot = bo[bk] + off;
            lrec[slot] = (u32x4){rec[q].x, rec[q].y, rec[q].z, rec[q].w};
            gaddr[slot] = bg[bk] + off;
        }
    }
    __syncthreads();
    int total = sct[255];                          // records in this block
    for (int s = t; s < total; s += P1_T) {
        u32x4 r = lrec[s];
        stg[gaddr[s]] = make_uint4(r.x, r.y, r.z, r.w);
    }
}

// fused sort+gather: one 1024-thread block per bucket. The bucket's ~8192
// records (<= CAP, +8.5 sigma margin) are node-sorted INTO LDS (one ds
// atomicSub per record), then each of 16 waves gathers 16 nodes reading
// records straight from LDS — csr never touches HBM (saves 51MB round-trip).
// Gather math = k_gather v3 (x-aggregation, projection through W_gat after).
__global__ __launch_bounds__(1024) void k_scat2g(const int* __restrict__ rowptr,
                                                 const int* __restrict__ bbase,
                                                 const uint4* __restrict__ stg,
                                                 const float* __restrict__ x,
                                                 const float* __restrict__ a_src,
                                                 const float* __restrict__ a_dst,
                                                 const float* __restrict__ W_gat,
                                                 const float* __restrict__ bias_gat,
                                                 float2* __restrict__ h_buf) {
    __shared__ int rp[257];
    __shared__ int lcnt[256];
    __shared__ u32x4 lrec[CAP];      // 140KB bucket-local CSR
    int b = blockIdx.x, t = threadIdx.x;
    int n0 = b << 8;
    int nn = min(256, N_NODES - n0);
    int base = bbase[b];
    for (int i = t; i <= nn; i += 1024) rp[i] = rowptr[n0 + i] - base;
    __syncthreads();
    for (int i = t; i < nn; i += 1024) lcnt[i] = rp[i + 1] - rp[i];
    __syncthreads();
    int total = rp[nn];

    // phase 1: node-sort the stg slice into LDS (coalesced read, ~8 rec/thread)
    for (int e = t; e < total; e += 1024) {
        uint4 r = stg[base + e];
        int dl = (int)((r.z >> 16) & 0xFFu);
        int c = atomicSub(&lcnt[dl], 1);
        int slot = rp[dl] + c - 1;
        if (slot < CAP) lrec[slot] = (u32x4){r.x, r.y, r.z, r.w};
    }
    __syncthreads();

    // phase 2: wave wv gathers nodes wv*16 .. wv*16+15 from LDS
    int wv = t >> 6, l = t & 63;
    int h = l & 3;                 // aggregation head
    int slot = l >> 2;             // edge slot 0..15
    int c0 = 2 * l;
    float w00 = W_gat[c0],       w01 = W_gat[c0 + 1];
    float w10 = W_gat[128 + c0], w11 = W_gat[128 + c0 + 1];
    float w20 = W_gat[256 + c0], w21 = W_gat[256 + c0 + 1];
    float2 bia = ((const float2*)bias_gat)[l];

    #pragma unroll 1
    for (int j = 0; j < 16; ++j) {
        int i = wv * 16 + j;
        if (i >= nn) break;                        // wave-uniform
        int n = n0 + i;
        int start = rp[i], end = rp[i + 1];
        int deg = end - start;
        float ad_n = a_dst[n * 4 + h];
        float as_n = a_src[n * 4 + h];
        float sx0 = 0.f, sx1 = 0.f, sx2 = 0.f, den = 0.f, aes = 0.f;

        for (int p0 = start; p0 < end; p0 += 16) {
            int e = p0 + slot;
            float w = 0.f, ae = 0.f;
            int src = n;
            if (e < end) {
                u32x4 rc = lrec[e];
                uint32_t aw = (h < 2) ? rc.x : rc.y;
                float comb = (h & 1) ? bfhi(aw) : bflo(aw);   // ae + a_src[src]
                ae = e4m32f((rc.w >> (h * 8)) & 0xffu);
                src = (int)(rc.z & 0xFFFFu);
                float al = comb + ad_n;
                al = al > 0.f ? al : NEG_SLOPE * al;
                w = __expf(al);
            }
            const float* xr = x + src * 3;                    // L2-hot table
            sx0 += w * xr[0];
            sx1 += w * xr[1];
            sx2 += w * xr[2];
            den += w;
            aes += ae;
        }

        // allreduce across the 16 slots (lanes with equal l&3)
        #pragma unroll
        for (int m = 4; m <= 32; m <<= 1) {
            sx0 += __shfl_xor(sx0, m);
            sx1 += __shfl_xor(sx1, m);
            sx2 += __shfl_xor(sx2, m);
            den += __shfl_xor(den, m);
            aes += __shfl_xor(aes, m);
        }

        // self loop: edge_attr = mean of incoming aeh
        float xn0 = x[n * 3], xn1 = x[n * 3 + 1], xn2 = x[n * 3 + 2];
        float invd = (deg > 0) ? (1.0f / (float)deg) : 1.0f;
        float alS = as_n + ad_n + aes * invd;
        alS = alS > 0.f ? alS : NEG_SLOPE * alS;
        float wS = __expf(alS);
        sx0 += wS * xn0; sx1 += wS * xn1; sx2 += wS * xn2;
        den += wS;

        // lane l needs head l>>4 totals (all lanes hold their head's total)
        int sb = (l >> 4) << 2;
        float t0 = bpermf(sb, sx0);
        float t1 = bpermf(sb, sx1);
        float t2 = bpermf(sb, sx2);
        float td = bpermf(sb, den);

        float r = 1.0f / td;
        float o0 = (t0 * w00 + t1 * w10 + t2 * w20) * r + bia.x;
        float o1 = (t0 * w01 + t1 * w11 + t2 * w21) * r + bia.y;
        o0 = o0 > 0.f ? o0 : (__expf(o0) - 1.0f);   // ELU
        o1 = o1 > 0.f ? o1 : (__expf(o1) - 1.0f);
        h_buf[(size_t)n * 64 + l] = make_float2(o0, o1);
    }
}

// MFMA MLP: 32 rows/block, 4 waves. bf16 hi/lo split (3-term) for ~fp32
// accuracy at matrix-pipe rate. LDS planes [32][136] bf16 (row stride 272B).
__global__ __launch_bounds__(256) void k_mlp(const float* __restrict__ h_buf,
                                             const uint16_t* __restrict__ W1T_hi,
                                             const uint16_t* __restrict__ W1T_lo,
                                             const uint16_t* __restrict__ W2T_hi,
                                             const uint16_t* __restrict__ W2T_lo,
                                             const float* __restrict__ b1,
                                             const float* __restrict__ prelu_a,
                                             const float* __restrict__ b2,
                                             float* __restrict__ out) {
    __shared__ uint16_t hHi[32 * 136];
    __shared__ uint16_t hLo[32 * 136];
    __shared__ uint16_t h1Hi[32 * 136];
    __shared__ uint16_t h1Lo[32 * 136];
    int t = threadIdx.x;
    int nb = blockIdx.x * 32;

    // stage h rows -> bf16 hi/lo planes
    const float4* hb4 = (const float4*)(h_buf + (size_t)nb * 128);
    #pragma unroll
    for (int i = 0; i < 4; ++i) {
        int idx = i * 256 + t;             // float4 index, 1024 total
        int row = idx >> 5, c4 = idx & 31;
        float4 v = make_float4(0.f, 0.f, 0.f, 0.f);
        if (nb + row < N_NODES) v = hb4[idx];
        float xs[4] = {v.x, v.y, v.z, v.w};
        uint32_t hi[4], lo[4];
        #pragma unroll
        for (int j = 0; j < 4; ++j) {
            hi[j] = f2bf(xs[j]);
            lo[j] = f2bf(xs[j] - bflo(hi[j]));
        }
        uint32_t bo = row * 272 + c4 * 8;
        *(uint2*)((char*)hHi + bo) = make_uint2(hi[0] | (hi[1] << 16), hi[2] | (hi[3] << 16));
        *(uint2*)((char*)hLo + bo) = make_uint2(lo[0] | (lo[1] << 16), lo[2] | (lo[3] << 16));
    }
    __syncthreads();

    int w = t >> 6, l = t & 63;
    int lr = l & 15, lg = l >> 4;          // frag row/col lane, k-group
    // ---- layer 1: wave w -> col-tiles {2w, 2w+1}, both row-tiles ----
    float bb0 = b1[(2 * w) * 16 + lr];
    float bb1 = b1[(2 * w + 1) * 16 + lr];
    f32x4 acc[2][2];
    #pragma unroll
    for (int rt = 0; rt < 2; ++rt) {
        acc[rt][0] = (f32x4){bb0, bb0, bb0, bb0};
        acc[rt][1] = (f32x4){bb1, bb1, bb1, bb1};
    }
    #pragma unroll
    for (int s = 0; s < 4; ++s) {
        int koff = s * 64 + lg * 16;       // byte offset of k-chunk
        bf16x8 a_hi[2], a_lo[2], b_hi[2], b_lo[2];
        #pragma unroll
        for (int rt = 0; rt < 2; ++rt) {
            int ro = (rt * 16 + lr) * 272 + koff;
            a_hi[rt] = *(const bf16x8*)((const char*)hHi + ro);
            a_lo[rt] = *(const bf16x8*)((const char*)hLo + ro);
        }
        #pragma unroll
        for (int c = 0; c < 2; ++c) {
            int go = ((2 * w + c) * 16 + lr) * 256 + koff;
            b_hi[c] = *(const bf16x8*)((const char*)W1T_hi + go);
            b_lo[c] = *(const bf16x8*)((const char*)W1T_lo + go);
        }
        #pragma unroll
        for (int rt = 0; rt < 2; ++rt)
            #pragma unroll
            for (int c = 0; c < 2; ++c) {
                acc[rt][c] = __builtin_amdgcn_mfma_f32_16x16x32_bf16(a_hi[rt], b_hi[c], acc[rt][c], 0, 0, 0);
                acc[rt][c] = __builtin_amdgcn_mfma_f32_16x16x32_bf16(a_hi[rt], b_lo[c], acc[rt][c], 0, 0, 0);
                acc[rt][c] = __builtin_amdgcn_mfma_f32_16x16x32_bf16(a_lo[rt], b_hi[c], acc[rt][c], 0, 0, 0);
            }
    }
    // PReLU + re-split -> h1 planes
    float pa = prelu_a[0];
    #pragma unroll
    for (int rt = 0; rt < 2; ++rt)
        #pragma unroll
        for (int c = 0; c < 2; ++c) {
            int n = (2 * w + c) * 16 + lr;
            #pragma unroll
            for (int r = 0; r < 4; ++r) {
                float vv = acc[rt][c][r];
                vv = vv > 0.f ? vv : pa * vv;
                uint32_t hi = f2bf(vv);
                uint32_t lo = f2bf(vv - bflo(hi));
                int m = rt * 16 + lg * 4 + r;
                uint32_t bo = m * 272 + n * 2;
                *(uint16_t*)((char*)h1Hi + bo) = (uint16_t)hi;
                *(uint16_t*)((char*)h1Lo + bo) = (uint16_t)lo;
            }
        }
    __syncthreads();
    // ---- layer 2: wave w -> tile (rt = w&1, ct = w>>1) ----
    int rt2 = w & 1, ct2 = w >> 1;
    float bb2 = b2[ct2 * 16 + lr];
    f32x4 acc2 = (f32x4){bb2, bb2, bb2, bb2};
    #pragma unroll
    for (int s = 0; s < 4; ++s) {
        int koff = s * 64 + lg * 16;
        int ro = (rt2 * 16 + lr) * 272 + koff;
        bf16x8 a_hi = *(const bf16x8*)((const char*)h1Hi + ro);
        bf16x8 a_lo = *(const bf16x8*)((const char*)h1Lo + ro);
        int go = (ct2 * 16 + lr) * 256 + koff;
        bf16x8 w2h = *(const bf16x8*)((const char*)W2T_hi + go);
        bf16x8 w2l = *(const bf16x8*)((const char*)W2T_lo + go);
        acc2 = __builtin_amdgcn_mfma_f32_16x16x32_bf16(a_hi, w2h, acc2, 0, 0, 0);
        acc2 = __builtin_amdgcn_mfma_f32_16x16x32_bf16(a_hi, w2l, acc2, 0, 0, 0);
        acc2 = __builtin_amdgcn_mfma_f32_16x16x32_bf16(a_lo, w2h, acc2, 0, 0, 0);
    }
    #pragma unroll
    for (int r = 0; r < 4; ++r) {
        int m = rt2 * 16 + lg * 4 + r;
        if (nb + m < N_NODES)
            out[(size_t)(nb + m) * 32 + ct2 * 16 + lr] = acc2[r];
    }
}

// ---------------------------------------------------------------- launch

extern "C" void kernel_launch(void* const* d_in, const int* in_sizes, int n_in,
                              void* d_out, int out_size, void* d_ws, size_t ws_size,
                              hipStream_t stream) {
    const float* x        = (const float*)d_in[0];
    const int*   ei       = (const int*)d_in[1];     // int32 per harness contract
    const float* edge_attr= (const float*)d_in[2];
    const float* W_gat    = (const float*)d_in[3];
    const float* att_src  = (const float*)d_in[4];
    const float* att_dst  = (const float*)d_in[5];
    const float* W_edge   = (const float*)d_in[6];
    const float* att_edge = (const float*)d_in[7];
    const float* bias_gat = (const float*)d_in[8];
    const float* W1       = (const float*)d_in[9];
    const float* b1       = (const float*)d_in[10];
    const float* prelu_a  = (const float*)d_in[11];
    const float* W2       = (const float*)d_in[12];
    const float* b2       = (const float*)d_in[13];
    float*       out      = (float*)d_out;

    char* base = (char*)d_ws;
    size_t off = 0;
    auto alloc = [&](size_t bytes) -> void* {
        void* p = base + off;
        off = (off + bytes + 255) & ~(size_t)255;
        return p;
    };
    int*      cnt     = (int*)     alloc((size_t)N_NODES * 4);
    int*      rowptr  = (int*)     alloc((size_t)(N_NODES + 1) * 4);
    int*      bcur    = (int*)     alloc((size_t)NBUCK * 4);
    int*      bsum    = (int*)     alloc((size_t)NBUCK * 4);
    int*      bbase   = (int*)     alloc((size_t)(NBUCK + 1) * 4);
    float*    v       = (float*)   alloc(32 * 4);
    uint16_t* W1T_hi  = (uint16_t*)alloc((size_t)128 * 128 * 2);
    uint16_t* W1T_lo  = (uint16_t*)alloc((size_t)128 * 128 * 2);
    uint16_t* W2T_hi  = (uint16_t*)alloc((size_t)32 * 128 * 2);
    uint16_t* W2T_lo  = (uint16_t*)alloc((size_t)32 * 128 * 2);
    float*    a_src   = (float*)   alloc((size_t)N_NODES * 4 * 4);
    float*    a_dst   = (float*)   alloc((size_t)N_NODES * 4 * 4);
    float*    h_buf   = (float*)   alloc((size_t)N_NODES * 128 * 4);
    // staging aliases the hist buffer: hist is dead after k_red, staging is
    // written only after k_local. region = max(25.0MB hist, 25.6MB staging).
    size_t stg_bytes  = (size_t)N_EDGES * 16;
    size_t hist_bytes = (size_t)NB_HIST * N_NODES * 2;
    void* stg_region  = alloc(stg_bytes > hist_bytes ? stg_bytes : hist_bytes);
    uint16_t* hist    = (uint16_t*)stg_region;
    uint4*    stg     = (uint4*)stg_region;

    k_pre   <<<NB_PRE, 256, 0, stream>>>(x, ei, W_gat, att_src, att_dst,
                                         W_edge, att_edge, W1, W2, hist,
                                         (float4*)a_src, (float4*)a_dst, v,
                                         W1T_hi, W1T_lo, W2T_hi, W2T_lo);
    k_red   <<<NBUCK, 256, 0, stream>>>(hist, cnt, bsum);
    k_scanb <<<1, 256, 0, stream>>>(bsum, bbase);
    k_local <<<NBUCK, 256, 0, stream>>>(cnt, bbase, rowptr, bcur);
    k_scat1 <<<P1_BLOCKS, P1_T, 0, stream>>>(
        ei, edge_attr, v, (const float4*)a_src, bcur, stg);
    k_scat2g<<<NBUCK, 1024, 0, stream>>>(
        rowptr, bbase, stg, x, a_src, a_dst, W_gat, bias_gat, (float2*)h_buf);
    k_mlp   <<<(N_NODES + 31) / 32, 256, 0, stream>>>(
        h_buf, W1T_hi, W1T_lo, W2T_hi, W2T_lo, b1, prelu_a, b2, out);
}